// Round 6
// baseline (526.922 us; speedup 1.0000x reference)
//
#include <hip/hip_runtime.h>
#include <cstdint>
#include <cstddef>

typedef float f32x4 __attribute__((ext_vector_type(4)));
typedef __bf16 bf16x8_t __attribute__((ext_vector_type(8)));
typedef short s16x8_t __attribute__((ext_vector_type(8)));
typedef unsigned short u16x4_t __attribute__((ext_vector_type(4)));

#define NN 8192   // nodes
#define FD 512    // in features
#define HD 256    // hidden
#define CD 40    // classes

static __device__ __forceinline__ unsigned short f2bf(float f) {
    unsigned int u = __builtin_bit_cast(unsigned int, f);
    u += 0x7FFFu + ((u >> 16) & 1u);          // round-to-nearest-even
    return (unsigned short)(u >> 16);
}
static __device__ __forceinline__ float bf2f(unsigned short s) {
    unsigned int u = ((unsigned int)s) << 16;
    return __builtin_bit_cast(float, u);
}

typedef __attribute__((address_space(3))) unsigned int lds_u32_t;
typedef __attribute__((address_space(1))) const unsigned int gbl_u32_t;
static __device__ __forceinline__ void gload16(const void* g, const void* lds) {
    __builtin_amdgcn_global_load_lds((gbl_u32_t*)g, (lds_u32_t*)lds, 16, 0, 0);
}

// ---------------- K-1: zero the rowsum accumulators ----------------
__global__ __launch_bounds__(256) void k_zero(float* __restrict__ S1,
                                              float* __restrict__ S2) {
    const int i = blockIdx.x * 256 + threadIdx.x;
    S1[i] = 0.f;
    S2[i] = 0.f;
}

// ---------------- K1: sup1 = x @ w1  (8192x512 @ 512x256, f32 vector) ----------------
__global__ __launch_bounds__(256) void k_xw1(const float* __restrict__ x,
                                             const float* __restrict__ w1,
                                             float* __restrict__ sup1) {
    __shared__ float xs[64][36];
    __shared__ float ws[32][68];
    const int m0 = (blockIdx.x >> 2) * 64;
    const int n0 = (blockIdx.x & 3) * 64;
    const int t = threadIdx.x;
    const int tx = t & 15, ty = t >> 4;
    float acc[4][4] = {};
    for (int k0 = 0; k0 < FD; k0 += 32) {
        for (int i = t; i < 512; i += 256) {
            int r = i >> 3, c = (i & 7) << 2;
            *(float4*)&xs[r][c] = *(const float4*)&x[(size_t)(m0 + r) * FD + k0 + c];
        }
        for (int i = t; i < 512; i += 256) {
            int r = i >> 4, c = (i & 15) << 2;
            *(float4*)&ws[r][c] = *(const float4*)&w1[(size_t)(k0 + r) * HD + n0 + c];
        }
        __syncthreads();
        for (int k = 0; k < 32; ++k) {
            float a_[4], b_[4];
            #pragma unroll
            for (int i = 0; i < 4; ++i) a_[i] = xs[ty * 4 + i][k];
            #pragma unroll
            for (int j = 0; j < 4; ++j) b_[j] = ws[k][tx * 4 + j];
            #pragma unroll
            for (int i = 0; i < 4; ++i)
                #pragma unroll
                for (int j = 0; j < 4; ++j) acc[i][j] += a_[i] * b_[j];
        }
        __syncthreads();
    }
    #pragma unroll
    for (int i = 0; i < 4; ++i)
        #pragma unroll
        for (int j = 0; j < 4; ++j)
            sup1[(size_t)(m0 + ty * 4 + i) * HD + n0 + tx * 4 + j] = acc[i][j];
}

// ---------------- K2: pack B1T[n][k] (bf16, 320 x 8192) = [sup1 | y | 0-pad]^T ----------------
__global__ __launch_bounds__(256) void k_packB1T(const float* __restrict__ sup1,
                                                 const float* __restrict__ y,
                                                 unsigned short* __restrict__ B1T) {
    __shared__ float tl[64][33];
    const int kt = blockIdx.x & 127;
    const int nt = blockIdx.x >> 7;
    const int k0 = kt * 64, n0 = nt * 32;
    const int t = threadIdx.x;
    {
        const int kr = t >> 2, cb = (t & 3) * 8;
        #pragma unroll
        for (int j = 0; j < 8; ++j) {
            const int n = n0 + cb + j;
            float v;
            if (n < 256)      v = sup1[(size_t)(k0 + kr) * HD + n];
            else if (n < 296) v = y[(size_t)(k0 + kr) * CD + (n - 256)];
            else              v = 0.f;
            tl[kr][cb + j] = v;
        }
    }
    __syncthreads();
    {
        const int nr = t >> 3, part = t & 7;
        unsigned short tmp[8];
        #pragma unroll
        for (int j = 0; j < 8; ++j) tmp[j] = f2bf(tl[part * 8 + j][nr]);
        *(s16x8_t*)&B1T[(size_t)(n0 + nr) * NN + k0 + part * 8] = *(s16x8_t*)tmp;
    }
}

// ---------------- K3: fused GEMM: A = bf16(adj .* mask) computed in-staging ----------------
// r5 post-mortem: the NTILES=5 variant was L2/latency-bound (5 column-siblings each
// re-reading the same f32 A-panel: 5x L2 traffic + MSHR hit-under-miss stalls on loads
// the wave synchronously waits on). The NTILES=1 variant (GEMM2 shape) measured fast.
// Fix: both GEMMs are NTILES=1 — one block owns the full N-width, every adj/mask byte
// staged exactly once chip-wide per K-slice. Wide BN raises MFMA/step (hides staging).
// MFMA core / fragments / C-epilogue identical to the verified k_gemm; fragment loop
// is per-nf so bfr stays transient (BN=320 would need 160 VGPR of bfr otherwise).
template<int BN, int WM, int WN, int SPLIT, int NTILES>
__global__ __launch_bounds__(256, (BN >= 320 ? 2 : 4)) void k_gemmF(
                                               const float* __restrict__ adj,
                                               const float* __restrict__ mask,
                                               const unsigned short* __restrict__ Bt,
                                               float* __restrict__ Cp,
                                               float* __restrict__ S) {
    constexpr int BM = 128, BK = 64;
    constexpr int MF = BM / (WM * 16);
    constexpr int NF = BN / (WN * 16);
    constexpr int NBI = BN / 32;          // B gload insts per wave
    constexpr int NSTR = NTILES * BN;     // Cp row stride
    constexpr int MT = NN / BM;           // 64 m-tiles
    __shared__ unsigned short As[BM * BK];
    __shared__ unsigned short Bs[BN * BK];
    int mt, ks, nt;
    if constexpr (NTILES > 1) {
        constexpr int NXCD = 8;
        constexpr int PAIRS = MT * SPLIT;              // (mt,ks) pairs
        constexpr int PPX = PAIRS / NXCD;              // pairs per XCD
        const int L = blockIdx.x;
        const int x = L % NXCD, q = L / NXCD;          // XCD id, slot on that XCD
        const int pr = x * PPX + q / NTILES;           // pair index
        nt = q % NTILES;
        mt = pr / SPLIT;
        ks = pr % SPLIT;
    } else {
        int b = blockIdx.x;
        nt = 0;
        ks = b % SPLIT;  b /= SPLIT;
        mt = b;
    }
    const int m0 = mt * BM, n0 = nt * BN;
    const int t = threadIdx.x, w = t >> 6, ln = t & 63;
    const int wn = w % WN, wm = w / WN;
    const int lrow = ln & 15, lkq = ln >> 4;
    const int kbeg = ks * (NN / SPLIT), kend = kbeg + (NN / SPLIT);
    const bool dosum = (NTILES == 1) || (nt == 0);

    // A-staging: granule g = t + i*256 (i<8) -> local row r = g>>4, q16 = g&15
    // (16 f32x4 granules per 64-col row). 16 lanes cover one row's 256B contiguously
    // per matrix -> fully coalesced. LDS target keeps the XOR chunk swizzle:
    // chunk cg = q16>>1 stored at slot cg^(r&7), half (q16&1).
    float rsum[8] = {};
    f32x4 acc[MF][NF] = {};
    for (int kb = kbeg; kb < kend; kb += BK) {
        f32x4 av[8], mv[8];
        #pragma unroll
        for (int i = 0; i < 8; ++i) {
            const int g = t + i * 256;
            const int r = g >> 4, q16 = g & 15;
            const size_t goff = (size_t)(m0 + r) * NN + kb + q16 * 4;
            av[i] = *(const f32x4*)&adj[goff];
            mv[i] = *(const f32x4*)&mask[goff];
        }
        // B stage (BN*128 bytes, direct-to-LDS)
        #pragma unroll
        for (int i = 0; i < NBI; ++i) {
            const int off = (w * NBI + i) * 1024 + ln * 16;
            const int r = off >> 7, ch = (off >> 4) & 7;
            gload16(Bt + (size_t)(n0 + r) * NN + kb + ((ch ^ (r & 7)) << 3),
                    &Bs[(w * NBI + i) * 512]);
        }
        f32x4 pr8[8];
        #pragma unroll
        for (int i = 0; i < 8; ++i) {
            #pragma unroll
            for (int e = 0; e < 4; ++e) pr8[i][e] = av[i][e] * mv[i][e];
        }
        if (dosum) {
            #pragma unroll
            for (int i = 0; i < 8; ++i)
                rsum[i] += fabsf(pr8[i][0]) + fabsf(pr8[i][1]) + fabsf(pr8[i][2]) + fabsf(pr8[i][3]);
        }
        #pragma unroll
        for (int i = 0; i < 8; ++i) {
            const int g = t + i * 256;
            const int r = g >> 4, q16 = g & 15;
            u16x4_t pk;
            pk.x = f2bf(pr8[i][0]); pk.y = f2bf(pr8[i][1]);
            pk.z = f2bf(pr8[i][2]); pk.w = f2bf(pr8[i][3]);
            *(u16x4_t*)&As[r * 64 + (((q16 >> 1) ^ (r & 7)) << 3) + ((q16 & 1) << 2)] = pk;
        }
        __syncthreads();   // drains vmcnt (gload_lds) + lgkmcnt (ds_write)

        bf16x8_t af[MF][2];
        #pragma unroll
        for (int mf = 0; mf < MF; ++mf)
            #pragma unroll
            for (int kh = 0; kh < 2; ++kh) {
                const int r = wm * (MF * 16) + mf * 16 + lrow;
                const int ch = (kh * 4 + lkq) ^ (r & 7);
                af[mf][kh] = __builtin_bit_cast(bf16x8_t, *(const s16x8_t*)&As[r * 64 + ch * 8]);
            }
        #pragma unroll
        for (int nf = 0; nf < NF; ++nf) {
            bf16x8_t bfr[2];
            #pragma unroll
            for (int kh = 0; kh < 2; ++kh) {
                const int r = wn * (NF * 16) + nf * 16 + lrow;
                const int ch = (kh * 4 + lkq) ^ (r & 7);
                bfr[kh] = __builtin_bit_cast(bf16x8_t, *(const s16x8_t*)&Bs[r * 64 + ch * 8]);
            }
            #pragma unroll
            for (int kh = 0; kh < 2; ++kh)
                #pragma unroll
                for (int mf = 0; mf < MF; ++mf)
                    acc[mf][nf] = __builtin_amdgcn_mfma_f32_16x16x32_bf16(
                        af[mf][kh], bfr[kh], acc[mf][nf], 0, 0, 0);
        }
        __syncthreads();
    }
    // epilogue: partial f32 store. C/D layout: col = lane&15 (from Bt row), row = (lane>>4)*4+e (from A row)
    #pragma unroll
    for (int mf = 0; mf < MF; ++mf)
        #pragma unroll
        for (int nf = 0; nf < NF; ++nf)
            #pragma unroll
            for (int e = 0; e < 4; ++e) {
                const int m = m0 + wm * (MF * 16) + mf * 16 + lkq * 4 + e;
                const int n = n0 + wn * (NF * 16) + nf * 16 + lrow;
                Cp[((size_t)ks * NN + m) * NSTR + n] = acc[mf][nf][e];
            }
    // rowsum commit: thread's granule rows are r(i) = w*4 + (ln>>4) + i*16;
    // 16 lanes (same ln>>4 group) share each row -> xor-reduce 1,2,4,8 then one atomic.
    if (dosum) {
        #pragma unroll
        for (int i = 0; i < 8; ++i) {
            float v = rsum[i];
            v += __shfl_xor(v, 1, 64);
            v += __shfl_xor(v, 2, 64);
            v += __shfl_xor(v, 4, 64);
            v += __shfl_xor(v, 8, 64);
            if ((ln & 15) == 0)
                atomicAdd(&S[m0 + w * 4 + (ln >> 4) + i * 16], v);
        }
    }
}

// ---------------- K4: finC — U1 = sum(8 Uc parts)/rowsum; h1 = relu(+b1) bf16; yh1 -> B2T rows 40..79 ----------------
__global__ __launch_bounds__(256) void k_finC(const float* __restrict__ U,   // [8][NN][320]
                                              const float* __restrict__ S1,  // raw rowsums
                                              const float* __restrict__ b1,
                                              unsigned short* __restrict__ h1,
                                              unsigned short* __restrict__ B2T) {
    const int t = threadIdx.x;
    const int r = t >> 3, l8 = t & 7;
    const int m = blockIdx.x * 32 + r;
    const float si = 1.0f / fmaxf(S1[m], 1e-12f);
    #pragma unroll
    for (int i = 0; i < 10; ++i) {
        const int c = (l8 + i * 8) * 4;       // 0..316
        f32x4 v = {};
        #pragma unroll
        for (int p = 0; p < 8; ++p) {
            f32x4 a = *(const f32x4*)&U[((size_t)p * NN + m) * 320 + c];
            #pragma unroll
            for (int e = 0; e < 4; ++e) v[e] += a[e];
        }
        #pragma unroll
        for (int e = 0; e < 4; ++e) v[e] *= si;
        if (i < 8) {                           // c < 256: hidden part
            u16x4_t pk;
            #pragma unroll
            for (int e = 0; e < 4; ++e) {
                const float hv = fmaxf(v[e] + b1[c + e], 0.f);
                ((unsigned short*)&pk)[e] = f2bf(hv);
            }
            *(u16x4_t*)&h1[(size_t)m * HD + c] = pk;
        } else {                               // c in 256..316: y_hat part
            #pragma unroll
            for (int e = 0; e < 4; ++e) {
                const int cc = c + e;
                if (cc < 296) B2T[(size_t)(40 + cc - 256) * NN + m] = f2bf(v[e]);
            }
        }
    }
}

// ---------------- K5: support2 = h1 @ w2 -> B2T rows 0..39 (transposed bf16); zero rows 80..95 ----------------
__global__ __launch_bounds__(256) void k_hw2(const unsigned short* __restrict__ h1,
                                             const float* __restrict__ w2,
                                             unsigned short* __restrict__ B2T) {
    __shared__ float w2s[HD * CD];
    __shared__ unsigned short h1s[32][264];
    __shared__ float ot[CD][33];
    const int t = threadIdx.x;
    const int mb = blockIdx.x * 32;
    for (int i = t; i < HD * CD; i += 256) w2s[i] = w2[i];
    for (int i = t; i < 1024; i += 256) {
        const int r = i >> 5, c = (i & 31) * 8;
        *(s16x8_t*)&h1s[r][c] = *(const s16x8_t*)&h1[(size_t)(mb + r) * HD + c];
    }
    __syncthreads();
    const int m = t >> 3, n0 = t & 7;
    float a5[5] = {};
    for (int k = 0; k < HD; ++k) {
        const float hv = bf2f(h1s[m][k]);
        #pragma unroll
        for (int j = 0; j < 5; ++j) a5[j] += hv * w2s[k * CD + n0 + 8 * j];
    }
    #pragma unroll
    for (int j = 0; j < 5; ++j) ot[n0 + 8 * j][m] = a5[j];
    __syncthreads();
    for (int i = t; i < CD * 32; i += 256) {
        const int n = i >> 5, mm = i & 31;
        B2T[(size_t)n * NN + mb + mm] = f2bf(ot[n][mm]);
    }
    for (int i = t; i < 16 * 32; i += 256)    // zero pad rows 80..95
        B2T[(size_t)(80 + (i >> 5)) * NN + mb + (i & 31)] = 0;
}

// ---------------- K6: finD — sum 16 partials, /rowsum, +b2, log_softmax both mats, store ----------------
__global__ __launch_bounds__(256) void k_finD(const float* __restrict__ U,   // [16][NN][96]
                                              const float* __restrict__ S2,  // raw rowsums
                                              const float* __restrict__ b2,
                                              float* __restrict__ out) {
    __shared__ float vt[32][100];
    const int t = threadIdx.x;
    const int mb = blockIdx.x * 32;
    for (int i = t; i < 32 * 24; i += 256) {
        const int r = i / 24, f4 = i % 24;
        const int m = mb + r;
        f32x4 s = {};
        #pragma unroll
        for (int p = 0; p < 16; ++p) {
            f32x4 v = *(const f32x4*)&U[((size_t)p * NN + m) * 96 + f4 * 4];
            #pragma unroll
            for (int e = 0; e < 4; ++e) s[e] += v[e];
        }
        const float si = 1.0f / fmaxf(S2[m], 1e-12f);
        #pragma unroll
        for (int e = 0; e < 4; ++e) {
            const int c = f4 * 4 + e;
            float v = s[e] * si;
            if (c < CD) v += b2[c];
            vt[r][c] = v;
        }
    }
    __syncthreads();
    const int l8 = t & 7;
    #pragma unroll
    for (int pass = 0; pass < 2; ++pass) {
        const int task = pass * 32 + (t >> 3);
        const int row = task & 31, mat = task >> 5;
        float vals[5];
        float mx = -3.0e38f;
        #pragma unroll
        for (int j = 0; j < 5; ++j) { vals[j] = vt[row][mat * CD + l8 + 8 * j]; mx = fmaxf(mx, vals[j]); }
        mx = fmaxf(mx, __shfl_xor(mx, 4, 8));
        mx = fmaxf(mx, __shfl_xor(mx, 2, 8));
        mx = fmaxf(mx, __shfl_xor(mx, 1, 8));
        float se = 0.f;
        #pragma unroll
        for (int j = 0; j < 5; ++j) se += expf(vals[j] - mx);
        se += __shfl_xor(se, 4, 8);
        se += __shfl_xor(se, 2, 8);
        se += __shfl_xor(se, 1, 8);
        const float ls = logf(se);
        float* op = out + (size_t)mat * (NN * CD) + (size_t)(mb + row) * CD;
        #pragma unroll
        for (int j = 0; j < 5; ++j) op[l8 + 8 * j] = vals[j] - mx - ls;
    }
}

extern "C" void kernel_launch(void* const* d_in, const int* in_sizes, int n_in,
                              void* d_out, int out_size, void* d_ws, size_t ws_size,
                              hipStream_t stream) {
    (void)in_sizes; (void)n_in; (void)out_size; (void)ws_size;
    const float* x     = (const float*)d_in[0];
    const float* adj   = (const float*)d_in[1];
    const float* y     = (const float*)d_in[2];
    const float* mask1 = (const float*)d_in[3];
    const float* mask2 = (const float*)d_in[4];
    const float* w1    = (const float*)d_in[5];
    const float* b1    = (const float*)d_in[6];
    const float* w2    = (const float*)d_in[7];
    const float* b2    = (const float*)d_in[8];
    float* out = (float*)d_out;

    char* p = (char*)d_ws;
    float*          sup1 = (float*)p;          p += 8388608;    // 8192x256 f32
    unsigned short* B1T  = (unsigned short*)p; p += 5242880;    // 320x8192 bf16
    unsigned short* h1   = (unsigned short*)p; p += 4194304;    // 8192x256 bf16
    unsigned short* B2T  = (unsigned short*)p; p += 1572864;    // 96x8192 bf16
    float*          U    = (float*)p;          p += 83886080;   // overlay: Uc[8][8192][320] (80MB) / Ud[16][8192][96] (48MB)
    float*          S1   = (float*)p;          p += 32768;      // raw rowsums |adj.*mask1|
    float*          S2   = (float*)p;          p += 32768;      // raw rowsums |adj.*mask2|

    hipLaunchKernelGGL(k_zero,    dim3(32),   dim3(256), 0, stream, S1, S2);
    hipLaunchKernelGGL(k_xw1,     dim3(512),  dim3(256), 0, stream, x, w1, sup1);
    hipLaunchKernelGGL(k_packB1T, dim3(1280), dim3(256), 0, stream, sup1, y, B1T);
    hipLaunchKernelGGL(HIP_KERNEL_NAME(k_gemmF<320, 4, 1, 8, 1>), dim3(512), dim3(256), 0, stream,
                       adj, mask1, B1T, U, S1);
    hipLaunchKernelGGL(k_finC,    dim3(256),  dim3(256), 0, stream, U, S1, b1, h1, B2T);
    hipLaunchKernelGGL(k_hw2,     dim3(256),  dim3(256), 0, stream, h1, w2, B2T);
    hipLaunchKernelGGL(HIP_KERNEL_NAME(k_gemmF<96, 4, 1, 16, 1>), dim3(1024), dim3(256), 0, stream,
                       adj, mask2, B2T, U, S2);
    hipLaunchKernelGGL(k_finD,    dim3(256),  dim3(256), 0, stream, U, S2, b2, out);
}

// Round 7
// 357.288 us; speedup vs baseline: 1.4748x; 1.4748x over previous
//
#include <hip/hip_runtime.h>
#include <cstdint>
#include <cstddef>

typedef float f32x4 __attribute__((ext_vector_type(4)));
typedef __bf16 bf16x8_t __attribute__((ext_vector_type(8)));
typedef short s16x8_t __attribute__((ext_vector_type(8)));
typedef unsigned short u16x4_t __attribute__((ext_vector_type(4)));

#define NN 8192   // nodes
#define FD 512    // in features
#define HD 256    // hidden
#define CD 40     // classes

static __device__ __forceinline__ unsigned short f2bf(float f) {
    unsigned int u = __builtin_bit_cast(unsigned int, f);
    u += 0x7FFFu + ((u >> 16) & 1u);          // round-to-nearest-even
    return (unsigned short)(u >> 16);
}
static __device__ __forceinline__ float bf2f(unsigned short s) {
    unsigned int u = ((unsigned int)s) << 16;
    return __builtin_bit_cast(float, u);
}

typedef __attribute__((address_space(3))) unsigned int lds_u32_t;
typedef __attribute__((address_space(1))) const unsigned int gbl_u32_t;
static __device__ __forceinline__ void gload16(const void* g, const void* lds) {
    __builtin_amdgcn_global_load_lds((gbl_u32_t*)g, (lds_u32_t*)lds, 16, 0, 0);
}

// ---------------- K0: fused prep + xw1 (heterogeneous grid) ----------------
// r6 post-mortem: fused-A GEMM refuted (3 shapes all ~280-330us, latency-bound).
// Reverted to the r3 pipeline (395us known-good). The one measured slack left is
// serialization: k_xw1 (~35us, compute-bound, disjoint data) ran AFTER k_prep
// (202us, HBM-bound, VALU 10%). Merge into one dispatch: blocks 0..511 run the
// xw1 body (dispatched first so they overlap inside prep's shadow), blocks
// 512..8703 run the prep body. Bodies are byte-identical to the verified r3
// kernels; no inter-half sync; outputs disjoint.
//
// prep notes (r1/r2 measured): NT loads + depth-1 SW pipeline = 202us,
// ~5.1 TB/s combined fabric (structural floor for 1.03 GB logical R+W).
// Per-row phase rotation REGRESSED (+12%) — do not decorrelate streams.
__global__ __launch_bounds__(256) void k_prep_xw1(
        const float* __restrict__ adj,
        const float* __restrict__ mask1,
        const float* __restrict__ mask2,     // may be null
        unsigned short* __restrict__ P1,
        unsigned short* __restrict__ P2,     // may be null
        float* __restrict__ sinv1,
        float* __restrict__ sinv2,           // may be null
        const float* __restrict__ x,
        const float* __restrict__ w1,
        float* __restrict__ sup1) {
    __shared__ float xs[64][36];
    __shared__ float ws[32][68];
    __shared__ float red1[4], red2[4];
    const int t = threadIdx.x;

    if (blockIdx.x < 512) {
        // ---- xw1 body: sup1 = x @ w1 (8192x512 @ 512x256) ----
        const int bid = blockIdx.x;
        const int m0 = (bid >> 2) * 64;
        const int n0 = (bid & 3) * 64;
        const int tx = t & 15, ty = t >> 4;
        float acc[4][4] = {};
        for (int k0 = 0; k0 < FD; k0 += 32) {
            for (int i = t; i < 512; i += 256) {
                int r = i >> 3, c = (i & 7) << 2;
                *(float4*)&xs[r][c] = *(const float4*)&x[(size_t)(m0 + r) * FD + k0 + c];
            }
            for (int i = t; i < 512; i += 256) {
                int r = i >> 4, c = (i & 15) << 2;
                *(float4*)&ws[r][c] = *(const float4*)&w1[(size_t)(k0 + r) * HD + n0 + c];
            }
            __syncthreads();
            for (int k = 0; k < 32; ++k) {
                float a_[4], b_[4];
                #pragma unroll
                for (int i = 0; i < 4; ++i) a_[i] = xs[ty * 4 + i][k];
                #pragma unroll
                for (int j = 0; j < 4; ++j) b_[j] = ws[k][tx * 4 + j];
                #pragma unroll
                for (int i = 0; i < 4; ++i)
                    #pragma unroll
                    for (int j = 0; j < 4; ++j) acc[i][j] += a_[i] * b_[j];
            }
            __syncthreads();
        }
        #pragma unroll
        for (int i = 0; i < 4; ++i)
            #pragma unroll
            for (int j = 0; j < 4; ++j)
                sup1[(size_t)(m0 + ty * 4 + i) * HD + n0 + tx * 4 + j] = acc[i][j];
        return;
    }

    // ---- prep body: P = bf16(adj .* mask), sinv = 1/max(rowsum|P|,eps) ----
    const int row = blockIdx.x - 512;
    const f32x4* __restrict__ ar  = (const f32x4*)(adj   + (size_t)row * NN);
    const f32x4* __restrict__ m1r = (const f32x4*)(mask1 + (size_t)row * NN);
    const f32x4* __restrict__ m2r = mask2 ? (const f32x4*)(mask2 + (size_t)row * NN) : nullptr;
    float s1 = 0.f, s2 = 0.f;

    f32x4 a  = __builtin_nontemporal_load(&ar[t]);
    f32x4 m1 = __builtin_nontemporal_load(&m1r[t]);
    f32x4 m2 = {};
    if (m2r) m2 = __builtin_nontemporal_load(&m2r[t]);

    #pragma unroll
    for (int j = 0; j < 8; ++j) {
        const int idx = j * 256 + t;
        f32x4 an = {}, m1n = {}, m2n = {};
        if (j < 7) {
            an  = __builtin_nontemporal_load(&ar[idx + 256]);
            m1n = __builtin_nontemporal_load(&m1r[idx + 256]);
            if (m2r) m2n = __builtin_nontemporal_load(&m2r[idx + 256]);
        }
        {
            const float p0 = a[0] * m1[0], p1 = a[1] * m1[1], p2 = a[2] * m1[2], p3 = a[3] * m1[3];
            s1 += fabsf(p0) + fabsf(p1) + fabsf(p2) + fabsf(p3);
            u16x4_t pk; pk.x = f2bf(p0); pk.y = f2bf(p1); pk.z = f2bf(p2); pk.w = f2bf(p3);
            *(u16x4_t*)&P1[(size_t)row * NN + idx * 4] = pk;
        }
        if (m2r) {
            const float p0 = a[0] * m2[0], p1 = a[1] * m2[1], p2 = a[2] * m2[2], p3 = a[3] * m2[3];
            s2 += fabsf(p0) + fabsf(p1) + fabsf(p2) + fabsf(p3);
            u16x4_t pk; pk.x = f2bf(p0); pk.y = f2bf(p1); pk.z = f2bf(p2); pk.w = f2bf(p3);
            *(u16x4_t*)&P2[(size_t)row * NN + idx * 4] = pk;
        }
        a = an; m1 = m1n; m2 = m2n;
    }
    // reduce across 256 threads
    #pragma unroll
    for (int d = 32; d; d >>= 1) { s1 += __shfl_xor(s1, d, 64); s2 += __shfl_xor(s2, d, 64); }
    if ((t & 63) == 0) { red1[t >> 6] = s1; red2[t >> 6] = s2; }
    __syncthreads();
    if (t == 0) {
        const float a1 = red1[0] + red1[1] + red1[2] + red1[3];
        sinv1[row] = 1.0f / fmaxf(a1, 1e-12f);
        if (sinv2) {
            const float a2 = red2[0] + red2[1] + red2[2] + red2[3];
            sinv2[row] = 1.0f / fmaxf(a2, 1e-12f);
        }
    }
}

// ---------------- K0b: standalone prep (second pass in !both mode) ----------------
__global__ __launch_bounds__(256) void k_prep(const float* __restrict__ adj,
                                              const float* __restrict__ mask1,
                                              const float* __restrict__ mask2,   // may be null
                                              unsigned short* __restrict__ P1,
                                              unsigned short* __restrict__ P2,   // may be null
                                              float* __restrict__ sinv1,
                                              float* __restrict__ sinv2) {       // may be null
    const int row = blockIdx.x;
    const int t = threadIdx.x;
    const f32x4* __restrict__ ar  = (const f32x4*)(adj   + (size_t)row * NN);
    const f32x4* __restrict__ m1r = (const f32x4*)(mask1 + (size_t)row * NN);
    const f32x4* __restrict__ m2r = mask2 ? (const f32x4*)(mask2 + (size_t)row * NN) : nullptr;
    float s1 = 0.f, s2 = 0.f;

    f32x4 a  = __builtin_nontemporal_load(&ar[t]);
    f32x4 m1 = __builtin_nontemporal_load(&m1r[t]);
    f32x4 m2 = {};
    if (m2r) m2 = __builtin_nontemporal_load(&m2r[t]);

    #pragma unroll
    for (int j = 0; j < 8; ++j) {
        const int idx = j * 256 + t;
        f32x4 an = {}, m1n = {}, m2n = {};
        if (j < 7) {
            an  = __builtin_nontemporal_load(&ar[idx + 256]);
            m1n = __builtin_nontemporal_load(&m1r[idx + 256]);
            if (m2r) m2n = __builtin_nontemporal_load(&m2r[idx + 256]);
        }
        {
            const float p0 = a[0] * m1[0], p1 = a[1] * m1[1], p2 = a[2] * m1[2], p3 = a[3] * m1[3];
            s1 += fabsf(p0) + fabsf(p1) + fabsf(p2) + fabsf(p3);
            u16x4_t pk; pk.x = f2bf(p0); pk.y = f2bf(p1); pk.z = f2bf(p2); pk.w = f2bf(p3);
            *(u16x4_t*)&P1[(size_t)row * NN + idx * 4] = pk;
        }
        if (m2r) {
            const float p0 = a[0] * m2[0], p1 = a[1] * m2[1], p2 = a[2] * m2[2], p3 = a[3] * m2[3];
            s2 += fabsf(p0) + fabsf(p1) + fabsf(p2) + fabsf(p3);
            u16x4_t pk; pk.x = f2bf(p0); pk.y = f2bf(p1); pk.z = f2bf(p2); pk.w = f2bf(p3);
            *(u16x4_t*)&P2[(size_t)row * NN + idx * 4] = pk;
        }
        a = an; m1 = m1n; m2 = m2n;
    }
    __shared__ float red1[4], red2[4];
    #pragma unroll
    for (int d = 32; d; d >>= 1) { s1 += __shfl_xor(s1, d, 64); s2 += __shfl_xor(s2, d, 64); }
    if ((t & 63) == 0) { red1[t >> 6] = s1; red2[t >> 6] = s2; }
    __syncthreads();
    if (t == 0) {
        const float a1 = red1[0] + red1[1] + red1[2] + red1[3];
        sinv1[row] = 1.0f / fmaxf(a1, 1e-12f);
        if (sinv2) {
            const float a2 = red2[0] + red2[1] + red2[2] + red2[3];
            sinv2[row] = 1.0f / fmaxf(a2, 1e-12f);
        }
    }
}

// ---------------- K2: pack B1T[n][k] (bf16, 320 x 8192) = [sup1 | y | 0-pad]^T ----------------
__global__ __launch_bounds__(256) void k_packB1T(const float* __restrict__ sup1,
                                                 const float* __restrict__ y,
                                                 unsigned short* __restrict__ B1T) {
    __shared__ float tl[64][33];
    const int kt = blockIdx.x & 127;
    const int nt = blockIdx.x >> 7;
    const int k0 = kt * 64, n0 = nt * 32;
    const int t = threadIdx.x;
    {
        const int kr = t >> 2, cb = (t & 3) * 8;
        #pragma unroll
        for (int j = 0; j < 8; ++j) {
            const int n = n0 + cb + j;
            float v;
            if (n < 256)      v = sup1[(size_t)(k0 + kr) * HD + n];
            else if (n < 296) v = y[(size_t)(k0 + kr) * CD + (n - 256)];
            else              v = 0.f;
            tl[kr][cb + j] = v;
        }
    }
    __syncthreads();
    {
        const int nr = t >> 3, part = t & 7;
        unsigned short tmp[8];
        #pragma unroll
        for (int j = 0; j < 8; ++j) tmp[j] = f2bf(tl[part * 8 + j][nr]);
        *(s16x8_t*)&B1T[(size_t)(n0 + nr) * NN + k0 + part * 8] = *(s16x8_t*)tmp;
    }
}

// ---------------- K3: m97-style GEMM: Cp[ks] = A[BM-tile] @ Bt^T (both row-major in K) ----------------
// BM=128, BK=64. XOR chunk-swizzle applied on the global source and on the ds_read (both-sides).
// For NTILES>1: XCD-grouping block remap (r3, measured win) so A-panel siblings share L2.
template<int BN, int WM, int WN, int SPLIT, int NTILES>
__global__ __launch_bounds__(256) void k_gemm(const unsigned short* __restrict__ A,
                                              const unsigned short* __restrict__ Bt,
                                              float* __restrict__ Cp) {
    constexpr int BM = 128, BK = 64;
    constexpr int MF = BM / (WM * 16);
    constexpr int NF = BN / (WN * 16);
    constexpr int NBI = BN / 32;          // B gload insts per wave
    constexpr int NSTR = NTILES * BN;     // Cp row stride
    constexpr int MT = NN / BM;           // 64 m-tiles
    __shared__ unsigned short As[BM * BK];
    __shared__ unsigned short Bs[BN * BK];
    int mt, ks, nt;
    if constexpr (NTILES > 1) {
        constexpr int NXCD = 8;
        constexpr int PAIRS = MT * SPLIT;              // (mt,ks) pairs
        static_assert(PAIRS % NXCD == 0, "pair count must split across XCDs");
        constexpr int PPX = PAIRS / NXCD;              // pairs per XCD
        const int L = blockIdx.x;
        const int x = L % NXCD, q = L / NXCD;          // XCD id, slot on that XCD
        const int pr = x * PPX + q / NTILES;           // pair index
        nt = q % NTILES;
        mt = pr / SPLIT;
        ks = pr % SPLIT;
    } else {
        int b = blockIdx.x;
        nt = 0;
        ks = b % SPLIT;  b /= SPLIT;
        mt = b;
    }
    const int m0 = mt * BM, n0 = nt * BN;
    const int t = threadIdx.x, w = t >> 6, ln = t & 63;
    const int wn = w % WN, wm = w / WN;
    const int lrow = ln & 15, lkq = ln >> 4;
    const int kbeg = ks * (NN / SPLIT), kend = kbeg + (NN / SPLIT);

    f32x4 acc[MF][NF] = {};
    for (int kb = kbeg; kb < kend; kb += BK) {
        // stage A (16KB): 16 wave-insts of 1KB; lane l -> LDS base + l*16
        #pragma unroll
        for (int i = 0; i < 4; ++i) {
            const int off = (w * 4 + i) * 1024 + ln * 16;
            const int r = off >> 7, ch = (off >> 4) & 7;
            gload16(A + (size_t)(m0 + r) * NN + kb + ((ch ^ (r & 7)) << 3),
                    &As[(w * 4 + i) * 512]);
        }
        // stage B (BN*128 bytes)
        #pragma unroll
        for (int i = 0; i < NBI; ++i) {
            const int off = (w * NBI + i) * 1024 + ln * 16;
            const int r = off >> 7, ch = (off >> 4) & 7;
            gload16(Bt + (size_t)(n0 + r) * NN + kb + ((ch ^ (r & 7)) << 3),
                    &Bs[(w * NBI + i) * 512]);
        }
        __syncthreads();   // compiler drains vmcnt before barrier

        bf16x8_t af[MF][2];
        #pragma unroll
        for (int mf = 0; mf < MF; ++mf)
            #pragma unroll
            for (int kh = 0; kh < 2; ++kh) {
                const int r = wm * (MF * 16) + mf * 16 + lrow;
                const int ch = (kh * 4 + lkq) ^ (r & 7);
                af[mf][kh] = __builtin_bit_cast(bf16x8_t, *(const s16x8_t*)&As[r * 64 + ch * 8]);
            }
        bf16x8_t bfr[NF][2];
        #pragma unroll
        for (int nf = 0; nf < NF; ++nf)
            #pragma unroll
            for (int kh = 0; kh < 2; ++kh) {
                const int r = wn * (NF * 16) + nf * 16 + lrow;
                const int ch = (kh * 4 + lkq) ^ (r & 7);
                bfr[nf][kh] = __builtin_bit_cast(bf16x8_t, *(const s16x8_t*)&Bs[r * 64 + ch * 8]);
            }
        #pragma unroll
        for (int kh = 0; kh < 2; ++kh)
            #pragma unroll
            for (int mf = 0; mf < MF; ++mf)
                #pragma unroll
                for (int nf = 0; nf < NF; ++nf)
                    acc[mf][nf] = __builtin_amdgcn_mfma_f32_16x16x32_bf16(
                        af[mf][kh], bfr[nf][kh], acc[mf][nf], 0, 0, 0);
        __syncthreads();
    }
    // epilogue: partial f32 store. C/D layout: col = lane&15 (from Bt row), row = (lane>>4)*4+e (from A row)
    #pragma unroll
    for (int mf = 0; mf < MF; ++mf)
        #pragma unroll
        for (int nf = 0; nf < NF; ++nf)
            #pragma unroll
            for (int e = 0; e < 4; ++e) {
                const int m = m0 + wm * (MF * 16) + mf * 16 + lkq * 4 + e;
                const int n = n0 + wn * (NF * 16) + nf * 16 + lrow;
                Cp[((size_t)ks * NN + m) * NSTR + n] = acc[mf][nf][e];
            }
}

// ---------------- K4: finC — U1 = sum(Uc parts)*sinv1; h1 = relu(+b1) bf16; yh1 -> B2T rows 40..79 ----------------
__global__ __launch_bounds__(256) void k_finC(const float* __restrict__ U,   // [2][NN][320]
                                              const float* __restrict__ sinv1,
                                              const float* __restrict__ b1,
                                              unsigned short* __restrict__ h1,
                                              unsigned short* __restrict__ B2T) {
    const int t = threadIdx.x;
    const int r = t >> 3, l8 = t & 7;
    const int m = blockIdx.x * 32 + r;
    const float si = sinv1[m];
    const float* __restrict__ u0 = U + (size_t)m * 320;
    const float* __restrict__ u1 = U + (size_t)(NN + m) * 320;
    #pragma unroll
    for (int i = 0; i < 10; ++i) {
        const int c = (l8 + i * 8) * 4;       // 0..316
        f32x4 a = *(const f32x4*)&u0[c];
        f32x4 b = *(const f32x4*)&u1[c];
        f32x4 v;
        #pragma unroll
        for (int e = 0; e < 4; ++e) v[e] = (a[e] + b[e]) * si;
        if (i < 8) {                           // c < 256: hidden part
            u16x4_t pk;
            #pragma unroll
            for (int e = 0; e < 4; ++e) {
                const float hv = fmaxf(v[e] + b1[c + e], 0.f);
                ((unsigned short*)&pk)[e] = f2bf(hv);
            }
            *(u16x4_t*)&h1[(size_t)m * HD + c] = pk;
        } else {                               // c in 256..316: y_hat part
            #pragma unroll
            for (int e = 0; e < 4; ++e) {
                const int cc = c + e;
                if (cc < 296) B2T[(size_t)(40 + cc - 256) * NN + m] = f2bf(v[e]);
            }
        }
    }
}

// ---------------- K5: support2 = h1 @ w2 -> B2T rows 0..39 (transposed bf16); zero rows 80..95 ----------------
__global__ __launch_bounds__(256) void k_hw2(const unsigned short* __restrict__ h1,
                                             const float* __restrict__ w2,
                                             unsigned short* __restrict__ B2T) {
    __shared__ float w2s[HD * CD];
    __shared__ unsigned short h1s[32][264];
    __shared__ float ot[CD][33];
    const int t = threadIdx.x;
    const int mb = blockIdx.x * 32;
    for (int i = t; i < HD * CD; i += 256) w2s[i] = w2[i];
    for (int i = t; i < 1024; i += 256) {
        const int r = i >> 5, c = (i & 31) * 8;
        *(s16x8_t*)&h1s[r][c] = *(const s16x8_t*)&h1[(size_t)(mb + r) * HD + c];
    }
    __syncthreads();
    const int m = t >> 3, n0 = t & 7;
    float a5[5] = {};
    for (int k = 0; k < HD; ++k) {
        const float hv = bf2f(h1s[m][k]);
        #pragma unroll
        for (int j = 0; j < 5; ++j) a5[j] += hv * w2s[k * CD + n0 + 8 * j];
    }
    #pragma unroll
    for (int j = 0; j < 5; ++j) ot[n0 + 8 * j][m] = a5[j];
    __syncthreads();
    for (int i = t; i < CD * 32; i += 256) {
        const int n = i >> 5, mm = i & 31;
        B2T[(size_t)n * NN + mb + mm] = f2bf(ot[n][mm]);
    }
    for (int i = t; i < 16 * 32; i += 256)    // zero pad rows 80..95
        B2T[(size_t)(80 + (i >> 5)) * NN + mb + (i & 31)] = 0;
}

// ---------------- K6: finD — sum 8 partials, *sinv2, +b2, log_softmax both mats, store ----------------
__global__ __launch_bounds__(256) void k_finD(const float* __restrict__ U,   // [8][NN][96]
                                              const float* __restrict__ sinv2,
                                              const float* __restrict__ b2,
                                              float* __restrict__ out) {
    __shared__ float vt[32][100];
    const int t = threadIdx.x;
    const int mb = blockIdx.x * 32;
    for (int i = t; i < 32 * 24; i += 256) {
        const int r = i / 24, f4 = i % 24;
        const int m = mb + r;
        f32x4 s = {};
        #pragma unroll
        for (int p = 0; p < 8; ++p) {
            f32x4 v = *(const f32x4*)&U[((size_t)p * NN + m) * 96 + f4 * 4];
            #pragma unroll
            for (int e = 0; e < 4; ++e) s[e] += v[e];
        }
        const float si = sinv2[m];
        #pragma unroll
        for (int e = 0; e < 4; ++e) {
            const int c = f4 * 4 + e;
            float v = s[e] * si;
            if (c < CD) v += b2[c];
            vt[r][c] = v;
        }
    }
    __syncthreads();
    const int l8 = t & 7;
    #pragma unroll
    for (int pass = 0; pass < 2; ++pass) {
        const int task = pass * 32 + (t >> 3);
        const int row = task & 31, mat = task >> 5;
        float vals[5];
        float mx = -3.0e38f;
        #pragma unroll
        for (int j = 0; j < 5; ++j) { vals[j] = vt[row][mat * CD + l8 + 8 * j]; mx = fmaxf(mx, vals[j]); }
        mx = fmaxf(mx, __shfl_xor(mx, 4, 8));
        mx = fmaxf(mx, __shfl_xor(mx, 2, 8));
        mx = fmaxf(mx, __shfl_xor(mx, 1, 8));
        float se = 0.f;
        #pragma unroll
        for (int j = 0; j < 5; ++j) se += expf(vals[j] - mx);
        se += __shfl_xor(se, 4, 8);
        se += __shfl_xor(se, 2, 8);
        se += __shfl_xor(se, 1, 8);
        const float ls = logf(se);
        float* op = out + (size_t)mat * (NN * CD) + (size_t)(mb + row) * CD;
        #pragma unroll
        for (int j = 0; j < 5; ++j) op[l8 + 8 * j] = vals[j] - mx - ls;
    }
}

extern "C" void kernel_launch(void* const* d_in, const int* in_sizes, int n_in,
                              void* d_out, int out_size, void* d_ws, size_t ws_size,
                              hipStream_t stream) {
    (void)in_sizes; (void)n_in; (void)out_size;
    const float* x     = (const float*)d_in[0];
    const float* adj   = (const float*)d_in[1];
    const float* y     = (const float*)d_in[2];
    const float* mask1 = (const float*)d_in[3];
    const float* mask2 = (const float*)d_in[4];
    const float* w1    = (const float*)d_in[5];
    const float* b1    = (const float*)d_in[6];
    const float* w2    = (const float*)d_in[7];
    const float* b2    = (const float*)d_in[8];
    float* out = (float*)d_out;

    const bool both = ws_size >= 313065472ULL;   // P1+P2 resident simultaneously
    char* p = (char*)d_ws;
    unsigned short* P1 = (unsigned short*)p; p += 134217728;
    unsigned short* P2 = P1;
    if (both) { P2 = (unsigned short*)p; p += 134217728; }
    float*          sup1 = (float*)p;          p += 8388608;    // 8192x256 f32
    unsigned short* B1T  = (unsigned short*)p; p += 5242880;    // 320x8192 bf16
    unsigned short* h1   = (unsigned short*)p; p += 4194304;    // 8192x256 bf16
    unsigned short* B2T  = (unsigned short*)p; p += 1572864;    // 96x8192 bf16
    float*          U    = (float*)p;          p += 25165824;   // overlay: Uc[2][8192][320] / Ud[8][8192][96]
    float*          sinv1 = (float*)p;         p += 32768;
    float*          sinv2 = (float*)p;         p += 32768;

    if (both) {
        hipLaunchKernelGGL(k_prep_xw1, dim3(8704), dim3(256), 0, stream,
                           adj, mask1, mask2, P1, P2, sinv1, sinv2, x, w1, sup1);
    } else {
        hipLaunchKernelGGL(k_prep_xw1, dim3(8704), dim3(256), 0, stream,
                           adj, mask1, (const float*)nullptr, P1, (unsigned short*)nullptr,
                           sinv1, (float*)nullptr, x, w1, sup1);
    }
    hipLaunchKernelGGL(k_packB1T, dim3(1280), dim3(256), 0, stream, sup1, y, B1T);
    hipLaunchKernelGGL(HIP_KERNEL_NAME(k_gemm<64, 2, 2, 2, 5>), dim3(640), dim3(256), 0, stream,
                       P1, B1T, U);
    hipLaunchKernelGGL(k_finC,    dim3(256),  dim3(256), 0, stream, U, sinv1, b1, h1, B2T);
    hipLaunchKernelGGL(k_hw2,     dim3(256),  dim3(256), 0, stream, h1, w2, B2T);
    if (!both) {
        hipLaunchKernelGGL(k_prep, dim3(8192), dim3(256), 0, stream,
                           adj, mask2, (const float*)nullptr, P1, (unsigned short*)nullptr,
                           sinv2, (float*)nullptr);
    }
    hipLaunchKernelGGL(HIP_KERNEL_NAME(k_gemm<96, 4, 1, 8, 1>), dim3(512), dim3(256), 0, stream,
                       P2, B2T, U);
    hipLaunchKernelGGL(k_finD,    dim3(256),  dim3(256), 0, stream, U, sinv2, b2, out);
}

// Round 8
// 340.283 us; speedup vs baseline: 1.5485x; 1.0500x over previous
//
#include <hip/hip_runtime.h>
#include <cstdint>
#include <cstddef>

typedef float f32x4 __attribute__((ext_vector_type(4)));
typedef __bf16 bf16x8_t __attribute__((ext_vector_type(8)));
typedef short s16x8_t __attribute__((ext_vector_type(8)));
typedef unsigned short u16x4_t __attribute__((ext_vector_type(4)));

#define NN 8192   // nodes
#define FD 512    // in features
#define HD 256    // hidden
#define CD 40     // classes

static __device__ __forceinline__ unsigned short f2bf(float f) {
    unsigned int u = __builtin_bit_cast(unsigned int, f);
    u += 0x7FFFu + ((u >> 16) & 1u);          // round-to-nearest-even
    return (unsigned short)(u >> 16);
}
static __device__ __forceinline__ float bf2f(unsigned short s) {
    unsigned int u = ((unsigned int)s) << 16;
    return __builtin_bit_cast(float, u);
}

typedef __attribute__((address_space(3))) unsigned int lds_u32_t;
typedef __attribute__((address_space(1))) const unsigned int gbl_u32_t;
static __device__ __forceinline__ void gload16(const void* g, const void* lds) {
    __builtin_amdgcn_global_load_lds((gbl_u32_t*)g, (lds_u32_t*)lds, 16, 0, 0);
}

// ---------------- K0: fused prep + xw1->B1T + ypack (heterogeneous grid) ----------------
// r7 measured: heterogeneous overlap works (xw1's 35us absorbed into prep's memory shadow
// for +10us). This round extends it: xw1 blocks write their output tile DIRECTLY into B1T
// (LDS transpose + bf16, same rounding point as the old packB1T), and 128 ypack blocks
// fill B1T rows 256..319 (y^T + zero pad) — those depend only on inputs. k_packB1T and the
// sup1 buffer are deleted. Block roles: 0..511 xw1, 512..639 ypack, 640..8831 prep.
//
// prep notes (r1/r2 measured): NT loads + depth-1 SW pipeline, ~5.0-5.1 TB/s combined
// fabric = floor for 1.05 GB logical R+W. Per-row phase rotation REGRESSED — keep lockstep.
__global__ __launch_bounds__(256) void k_prep_xw1(
        const float* __restrict__ adj,
        const float* __restrict__ mask1,
        const float* __restrict__ mask2,     // may be null
        unsigned short* __restrict__ P1,
        unsigned short* __restrict__ P2,     // may be null
        float* __restrict__ sinv1,
        float* __restrict__ sinv2,           // may be null
        const float* __restrict__ x,
        const float* __restrict__ w1,
        const float* __restrict__ y,
        unsigned short* __restrict__ B1T) {
    __shared__ char smem[18432];             // aliased per block role
    const int t = threadIdx.x;

    if (blockIdx.x < 512) {
        // ---- xw1 body: B1T[n][k] rows 0..255 = (x @ w1)^T, bf16 ----
        float (*xs)[36] = (float(*)[36])smem;            // 64x36 f32 = 9216 B
        float (*ws)[68] = (float(*)[68])(smem + 9216);   // 32x68 f32 = 8704 B
        const int bid = blockIdx.x;
        const int m0 = (bid >> 2) * 64;      // k-range of B1T
        const int n0 = (bid & 3) * 64;       // n-range of B1T
        const int tx = t & 15, ty = t >> 4;
        float acc[4][4] = {};
        for (int k0 = 0; k0 < FD; k0 += 32) {
            for (int i = t; i < 512; i += 256) {
                int r = i >> 3, c = (i & 7) << 2;
                *(float4*)&xs[r][c] = *(const float4*)&x[(size_t)(m0 + r) * FD + k0 + c];
            }
            for (int i = t; i < 512; i += 256) {
                int r = i >> 4, c = (i & 15) << 2;
                *(float4*)&ws[r][c] = *(const float4*)&w1[(size_t)(k0 + r) * HD + n0 + c];
            }
            __syncthreads();
            for (int k = 0; k < 32; ++k) {
                float a_[4], b_[4];
                #pragma unroll
                for (int i = 0; i < 4; ++i) a_[i] = xs[ty * 4 + i][k];
                #pragma unroll
                for (int j = 0; j < 4; ++j) b_[j] = ws[k][tx * 4 + j];
                #pragma unroll
                for (int i = 0; i < 4; ++i)
                    #pragma unroll
                    for (int j = 0; j < 4; ++j) acc[i][j] += a_[i] * b_[j];
            }
            __syncthreads();
        }
        // transpose via LDS (reuse smem; xs/ws dead after last sync), then bf16 -> B1T
        float (*ot)[65] = (float(*)[65])smem;            // 64x65 f32 = 16640 B
        #pragma unroll
        for (int i = 0; i < 4; ++i)
            #pragma unroll
            for (int j = 0; j < 4; ++j)
                ot[tx * 4 + j][ty * 4 + i] = acc[i][j];  // ot[n_local][m_local]
        __syncthreads();
        #pragma unroll
        for (int u = 0; u < 2; ++u) {
            const int task = t + u * 256;                // 512 tasks
            const int nr = task >> 3, part = task & 7;
            unsigned short tmp[8];
            #pragma unroll
            for (int j = 0; j < 8; ++j) tmp[j] = f2bf(ot[nr][part * 8 + j]);
            *(s16x8_t*)&B1T[(size_t)(n0 + nr) * NN + m0 + part * 8] = *(s16x8_t*)tmp;
        }
        return;
    }

    if (blockIdx.x < 640) {
        // ---- ypack body: B1T rows 256..295 = y^T ; rows 296..319 = 0 ----
        float (*tl)[41] = (float(*)[41])smem;            // 64x41 f32 = 10496 B
        const int k0 = (blockIdx.x - 512) * 64;
        for (int u = 0; u < 10; ++u) {                   // 64x40 = 2560 floats, coalesced
            const int idx = t + u * 256;
            tl[idx / 40][idx % 40] = y[(size_t)k0 * CD + idx];
        }
        __syncthreads();
        for (int task = t; task < 320; task += 256) {    // 40 rows x 8 parts
            const int c = task >> 3, part = task & 7;
            unsigned short tmp[8];
            #pragma unroll
            for (int j = 0; j < 8; ++j) tmp[j] = f2bf(tl[part * 8 + j][c]);
            *(s16x8_t*)&B1T[(size_t)(256 + c) * NN + k0 + part * 8] = *(s16x8_t*)tmp;
        }
        for (int task = t; task < 192; task += 256) {    // 24 zero rows x 8 parts
            const int row = 296 + (task >> 3), part = task & 7;
            s16x8_t z = {};
            *(s16x8_t*)&B1T[(size_t)row * NN + k0 + part * 8] = z;
        }
        return;
    }

    // ---- prep body: P = bf16(adj .* mask), sinv = 1/max(rowsum|P|,eps) ----
    float* red1 = (float*)smem;              // 4 floats
    float* red2 = (float*)(smem + 16);       // 4 floats
    const int row = blockIdx.x - 640;
    const f32x4* __restrict__ ar  = (const f32x4*)(adj   + (size_t)row * NN);
    const f32x4* __restrict__ m1r = (const f32x4*)(mask1 + (size_t)row * NN);
    const f32x4* __restrict__ m2r = mask2 ? (const f32x4*)(mask2 + (size_t)row * NN) : nullptr;
    float s1 = 0.f, s2 = 0.f;

    f32x4 a  = __builtin_nontemporal_load(&ar[t]);
    f32x4 m1 = __builtin_nontemporal_load(&m1r[t]);
    f32x4 m2 = {};
    if (m2r) m2 = __builtin_nontemporal_load(&m2r[t]);

    #pragma unroll
    for (int j = 0; j < 8; ++j) {
        const int idx = j * 256 + t;
        f32x4 an = {}, m1n = {}, m2n = {};
        if (j < 7) {
            an  = __builtin_nontemporal_load(&ar[idx + 256]);
            m1n = __builtin_nontemporal_load(&m1r[idx + 256]);
            if (m2r) m2n = __builtin_nontemporal_load(&m2r[idx + 256]);
        }
        {
            const float p0 = a[0] * m1[0], p1 = a[1] * m1[1], p2 = a[2] * m1[2], p3 = a[3] * m1[3];
            s1 += fabsf(p0) + fabsf(p1) + fabsf(p2) + fabsf(p3);
            u16x4_t pk; pk.x = f2bf(p0); pk.y = f2bf(p1); pk.z = f2bf(p2); pk.w = f2bf(p3);
            *(u16x4_t*)&P1[(size_t)row * NN + idx * 4] = pk;
        }
        if (m2r) {
            const float p0 = a[0] * m2[0], p1 = a[1] * m2[1], p2 = a[2] * m2[2], p3 = a[3] * m2[3];
            s2 += fabsf(p0) + fabsf(p1) + fabsf(p2) + fabsf(p3);
            u16x4_t pk; pk.x = f2bf(p0); pk.y = f2bf(p1); pk.z = f2bf(p2); pk.w = f2bf(p3);
            *(u16x4_t*)&P2[(size_t)row * NN + idx * 4] = pk;
        }
        a = an; m1 = m1n; m2 = m2n;
    }
    #pragma unroll
    for (int d = 32; d; d >>= 1) { s1 += __shfl_xor(s1, d, 64); s2 += __shfl_xor(s2, d, 64); }
    if ((t & 63) == 0) { red1[t >> 6] = s1; red2[t >> 6] = s2; }
    __syncthreads();
    if (t == 0) {
        const float a1 = red1[0] + red1[1] + red1[2] + red1[3];
        sinv1[row] = 1.0f / fmaxf(a1, 1e-12f);
        if (sinv2) {
            const float a2 = red2[0] + red2[1] + red2[2] + red2[3];
            sinv2[row] = 1.0f / fmaxf(a2, 1e-12f);
        }
    }
}

// ---------------- K0b: standalone prep (second pass in !both mode) ----------------
__global__ __launch_bounds__(256) void k_prep(const float* __restrict__ adj,
                                              const float* __restrict__ mask1,
                                              const float* __restrict__ mask2,   // may be null
                                              unsigned short* __restrict__ P1,
                                              unsigned short* __restrict__ P2,   // may be null
                                              float* __restrict__ sinv1,
                                              float* __restrict__ sinv2) {       // may be null
    const int row = blockIdx.x;
    const int t = threadIdx.x;
    const f32x4* __restrict__ ar  = (const f32x4*)(adj   + (size_t)row * NN);
    const f32x4* __restrict__ m1r = (const f32x4*)(mask1 + (size_t)row * NN);
    const f32x4* __restrict__ m2r = mask2 ? (const f32x4*)(mask2 + (size_t)row * NN) : nullptr;
    float s1 = 0.f, s2 = 0.f;

    f32x4 a  = __builtin_nontemporal_load(&ar[t]);
    f32x4 m1 = __builtin_nontemporal_load(&m1r[t]);
    f32x4 m2 = {};
    if (m2r) m2 = __builtin_nontemporal_load(&m2r[t]);

    #pragma unroll
    for (int j = 0; j < 8; ++j) {
        const int idx = j * 256 + t;
        f32x4 an = {}, m1n = {}, m2n = {};
        if (j < 7) {
            an  = __builtin_nontemporal_load(&ar[idx + 256]);
            m1n = __builtin_nontemporal_load(&m1r[idx + 256]);
            if (m2r) m2n = __builtin_nontemporal_load(&m2r[idx + 256]);
        }
        {
            const float p0 = a[0] * m1[0], p1 = a[1] * m1[1], p2 = a[2] * m1[2], p3 = a[3] * m1[3];
            s1 += fabsf(p0) + fabsf(p1) + fabsf(p2) + fabsf(p3);
            u16x4_t pk; pk.x = f2bf(p0); pk.y = f2bf(p1); pk.z = f2bf(p2); pk.w = f2bf(p3);
            *(u16x4_t*)&P1[(size_t)row * NN + idx * 4] = pk;
        }
        if (m2r) {
            const float p0 = a[0] * m2[0], p1 = a[1] * m2[1], p2 = a[2] * m2[2], p3 = a[3] * m2[3];
            s2 += fabsf(p0) + fabsf(p1) + fabsf(p2) + fabsf(p3);
            u16x4_t pk; pk.x = f2bf(p0); pk.y = f2bf(p1); pk.z = f2bf(p2); pk.w = f2bf(p3);
            *(u16x4_t*)&P2[(size_t)row * NN + idx * 4] = pk;
        }
        a = an; m1 = m1n; m2 = m2n;
    }
    __shared__ float red1[4], red2[4];
    #pragma unroll
    for (int d = 32; d; d >>= 1) { s1 += __shfl_xor(s1, d, 64); s2 += __shfl_xor(s2, d, 64); }
    if ((t & 63) == 0) { red1[t >> 6] = s1; red2[t >> 6] = s2; }
    __syncthreads();
    if (t == 0) {
        const float a1 = red1[0] + red1[1] + red1[2] + red1[3];
        sinv1[row] = 1.0f / fmaxf(a1, 1e-12f);
        if (sinv2) {
            const float a2 = red2[0] + red2[1] + red2[2] + red2[3];
            sinv2[row] = 1.0f / fmaxf(a2, 1e-12f);
        }
    }
}

// ---------------- K3: m97-style GEMM: Cp[ks] = A[BM-tile] @ Bt^T (both row-major in K) ----------------
// BM=128, BK=64. XOR chunk-swizzle applied on the global source and on the ds_read (both-sides).
// For NTILES>1: XCD-grouping block remap (r3, measured win) so A-panel siblings share L2.
template<int BN, int WM, int WN, int SPLIT, int NTILES>
__global__ __launch_bounds__(256) void k_gemm(const unsigned short* __restrict__ A,
                                              const unsigned short* __restrict__ Bt,
                                              float* __restrict__ Cp) {
    constexpr int BM = 128, BK = 64;
    constexpr int MF = BM / (WM * 16);
    constexpr int NF = BN / (WN * 16);
    constexpr int NBI = BN / 32;          // B gload insts per wave
    constexpr int NSTR = NTILES * BN;     // Cp row stride
    constexpr int MT = NN / BM;           // 64 m-tiles
    __shared__ unsigned short As[BM * BK];
    __shared__ unsigned short Bs[BN * BK];
    int mt, ks, nt;
    if constexpr (NTILES > 1) {
        constexpr int NXCD = 8;
        constexpr int PAIRS = MT * SPLIT;              // (mt,ks) pairs
        static_assert(PAIRS % NXCD == 0, "pair count must split across XCDs");
        constexpr int PPX = PAIRS / NXCD;              // pairs per XCD
        const int L = blockIdx.x;
        const int x = L % NXCD, q = L / NXCD;          // XCD id, slot on that XCD
        const int pr = x * PPX + q / NTILES;           // pair index
        nt = q % NTILES;
        mt = pr / SPLIT;
        ks = pr % SPLIT;
    } else {
        int b = blockIdx.x;
        nt = 0;
        ks = b % SPLIT;  b /= SPLIT;
        mt = b;
    }
    const int m0 = mt * BM, n0 = nt * BN;
    const int t = threadIdx.x, w = t >> 6, ln = t & 63;
    const int wn = w % WN, wm = w / WN;
    const int lrow = ln & 15, lkq = ln >> 4;
    const int kbeg = ks * (NN / SPLIT), kend = kbeg + (NN / SPLIT);

    f32x4 acc[MF][NF] = {};
    for (int kb = kbeg; kb < kend; kb += BK) {
        // stage A (16KB): 16 wave-insts of 1KB; lane l -> LDS base + l*16
        #pragma unroll
        for (int i = 0; i < 4; ++i) {
            const int off = (w * 4 + i) * 1024 + ln * 16;
            const int r = off >> 7, ch = (off >> 4) & 7;
            gload16(A + (size_t)(m0 + r) * NN + kb + ((ch ^ (r & 7)) << 3),
                    &As[(w * 4 + i) * 512]);
        }
        // stage B (BN*128 bytes)
        #pragma unroll
        for (int i = 0; i < NBI; ++i) {
            const int off = (w * NBI + i) * 1024 + ln * 16;
            const int r = off >> 7, ch = (off >> 4) & 7;
            gload16(Bt + (size_t)(n0 + r) * NN + kb + ((ch ^ (r & 7)) << 3),
                    &Bs[(w * NBI + i) * 512]);
        }
        __syncthreads();   // compiler drains vmcnt before barrier

        bf16x8_t af[MF][2];
        #pragma unroll
        for (int mf = 0; mf < MF; ++mf)
            #pragma unroll
            for (int kh = 0; kh < 2; ++kh) {
                const int r = wm * (MF * 16) + mf * 16 + lrow;
                const int ch = (kh * 4 + lkq) ^ (r & 7);
                af[mf][kh] = __builtin_bit_cast(bf16x8_t, *(const s16x8_t*)&As[r * 64 + ch * 8]);
            }
        bf16x8_t bfr[NF][2];
        #pragma unroll
        for (int nf = 0; nf < NF; ++nf)
            #pragma unroll
            for (int kh = 0; kh < 2; ++kh) {
                const int r = wn * (NF * 16) + nf * 16 + lrow;
                const int ch = (kh * 4 + lkq) ^ (r & 7);
                bfr[nf][kh] = __builtin_bit_cast(bf16x8_t, *(const s16x8_t*)&Bs[r * 64 + ch * 8]);
            }
        #pragma unroll
        for (int kh = 0; kh < 2; ++kh)
            #pragma unroll
            for (int mf = 0; mf < MF; ++mf)
                #pragma unroll
                for (int nf = 0; nf < NF; ++nf)
                    acc[mf][nf] = __builtin_amdgcn_mfma_f32_16x16x32_bf16(
                        af[mf][kh], bfr[nf][kh], acc[mf][nf], 0, 0, 0);
        __syncthreads();
    }
    // epilogue: partial f32 store. C/D layout: col = lane&15 (from Bt row), row = (lane>>4)*4+e (from A row)
    #pragma unroll
    for (int mf = 0; mf < MF; ++mf)
        #pragma unroll
        for (int nf = 0; nf < NF; ++nf)
            #pragma unroll
            for (int e = 0; e < 4; ++e) {
                const int m = m0 + wm * (MF * 16) + mf * 16 + lkq * 4 + e;
                const int n = n0 + wn * (NF * 16) + nf * 16 + lrow;
                Cp[((size_t)ks * NN + m) * NSTR + n] = acc[mf][nf][e];
            }
}

// ---------------- K4: fused finC + hw2 ----------------
// finC block b produces h1 rows b*32..b*32+31; hw2 block b consumes exactly those rows.
// Fuse: h1 lives only in LDS (identical bf16 values), global h1 buffer deleted.
__global__ __launch_bounds__(256) void k_finC2(const float* __restrict__ U,   // [2][NN][320]
                                               const float* __restrict__ sinv1,
                                               const float* __restrict__ b1,
                                               const float* __restrict__ w2,
                                               unsigned short* __restrict__ B2T) {
    __shared__ float w2s[HD * CD];                 // 40 KB
    __shared__ unsigned short h1s[32][264];        // 16.9 KB
    __shared__ float otp[CD][33];                  // 5.3 KB
    const int t = threadIdx.x;
    const int mb = blockIdx.x * 32;

    for (int i = t; i < HD * CD; i += 256) w2s[i] = w2[i];

    // ---- finC phase: U1 = sum(2 parts)*sinv1; h -> LDS bf16; yh1 -> B2T rows 40..79 ----
    {
        const int r = t >> 3, l8 = t & 7;
        const int m = mb + r;
        const float si = sinv1[m];
        const float* __restrict__ u0 = U + (size_t)m * 320;
        const float* __restrict__ u1 = U + (size_t)(NN + m) * 320;
        #pragma unroll
        for (int i = 0; i < 10; ++i) {
            const int c = (l8 + i * 8) * 4;       // 0..316
            f32x4 a = *(const f32x4*)&u0[c];
            f32x4 b = *(const f32x4*)&u1[c];
            f32x4 v;
            #pragma unroll
            for (int e = 0; e < 4; ++e) v[e] = (a[e] + b[e]) * si;
            if (i < 8) {                           // c < 256: hidden part -> LDS
                u16x4_t pk;
                #pragma unroll
                for (int e = 0; e < 4; ++e) {
                    const float hv = fmaxf(v[e] + b1[c + e], 0.f);
                    ((unsigned short*)&pk)[e] = f2bf(hv);
                }
                *(u16x4_t*)&h1s[r][c] = pk;
            } else {                               // c in 256..316: y_hat part
                #pragma unroll
                for (int e = 0; e < 4; ++e) {
                    const int cc = c + e;
                    if (cc < 296) B2T[(size_t)(40 + cc - 256) * NN + m] = f2bf(v[e]);
                }
            }
        }
    }
    __syncthreads();

    // ---- hw2 phase: support2 = h1 @ w2 -> B2T rows 0..39; zero rows 80..95 ----
    {
        const int m = t >> 3, n0 = t & 7;
        float a5[5] = {};
        for (int k = 0; k < HD; ++k) {
            const float hv = bf2f(h1s[m][k]);
            #pragma unroll
            for (int j = 0; j < 5; ++j) a5[j] += hv * w2s[k * CD + n0 + 8 * j];
        }
        #pragma unroll
        for (int j = 0; j < 5; ++j) otp[n0 + 8 * j][m] = a5[j];
    }
    __syncthreads();
    for (int i = t; i < CD * 32; i += 256) {
        const int n = i >> 5, mm = i & 31;
        B2T[(size_t)n * NN + mb + mm] = f2bf(otp[n][mm]);
    }
    for (int i = t; i < 16 * 32; i += 256)    // zero pad rows 80..95
        B2T[(size_t)(80 + (i >> 5)) * NN + mb + (i & 31)] = 0;
}

// ---------------- K6: finD — sum 8 partials, *sinv2, +b2, log_softmax both mats, store ----------------
__global__ __launch_bounds__(256) void k_finD(const float* __restrict__ U,   // [8][NN][96]
                                              const float* __restrict__ sinv2,
                                              const float* __restrict__ b2,
                                              float* __restrict__ out) {
    __shared__ float vt[32][100];
    const int t = threadIdx.x;
    const int mb = blockIdx.x * 32;
    for (int i = t; i < 32 * 24; i += 256) {
        const int r = i / 24, f4 = i % 24;
        const int m = mb + r;
        f32x4 s = {};
        #pragma unroll
        for (int p = 0; p < 8; ++p) {
            f32x4 v = *(const f32x4*)&U[((size_t)p * NN + m) * 96 + f4 * 4];
            #pragma unroll
            for (int e = 0; e < 4; ++e) s[e] += v[e];
        }
        const float si = sinv2[m];
        #pragma unroll
        for (int e = 0; e < 4; ++e) {
            const int c = f4 * 4 + e;
            float v = s[e] * si;
            if (c < CD) v += b2[c];
            vt[r][c] = v;
        }
    }
    __syncthreads();
    const int l8 = t & 7;
    #pragma unroll
    for (int pass = 0; pass < 2; ++pass) {
        const int task = pass * 32 + (t >> 3);
        const int row = task & 31, mat = task >> 5;
        float vals[5];
        float mx = -3.0e38f;
        #pragma unroll
        for (int j = 0; j < 5; ++j) { vals[j] = vt[row][mat * CD + l8 + 8 * j]; mx = fmaxf(mx, vals[j]); }
        mx = fmaxf(mx, __shfl_xor(mx, 4, 8));
        mx = fmaxf(mx, __shfl_xor(mx, 2, 8));
        mx = fmaxf(mx, __shfl_xor(mx, 1, 8));
        float se = 0.f;
        #pragma unroll
        for (int j = 0; j < 5; ++j) se += expf(vals[j] - mx);
        se += __shfl_xor(se, 4, 8);
        se += __shfl_xor(se, 2, 8);
        se += __shfl_xor(se, 1, 8);
        const float ls = logf(se);
        float* op = out + (size_t)mat * (NN * CD) + (size_t)(mb + row) * CD;
        #pragma unroll
        for (int j = 0; j < 5; ++j) op[l8 + 8 * j] = vals[j] - mx - ls;
    }
}

extern "C" void kernel_launch(void* const* d_in, const int* in_sizes, int n_in,
                              void* d_out, int out_size, void* d_ws, size_t ws_size,
                              hipStream_t stream) {
    (void)in_sizes; (void)n_in; (void)out_size;
    const float* x     = (const float*)d_in[0];
    const float* adj   = (const float*)d_in[1];
    const float* y     = (const float*)d_in[2];
    const float* mask1 = (const float*)d_in[3];
    const float* mask2 = (const float*)d_in[4];
    const float* w1    = (const float*)d_in[5];
    const float* b1    = (const float*)d_in[6];
    const float* w2    = (const float*)d_in[7];
    const float* b2    = (const float*)d_in[8];
    float* out = (float*)d_out;

    const bool both = ws_size >= 313065472ULL;   // P1+P2 resident simultaneously
    char* p = (char*)d_ws;
    unsigned short* P1 = (unsigned short*)p; p += 134217728;
    unsigned short* P2 = P1;
    if (both) { P2 = (unsigned short*)p; p += 134217728; }
    unsigned short* B1T  = (unsigned short*)p; p += 5242880;    // 320x8192 bf16
    unsigned short* B2T  = (unsigned short*)p; p += 1572864;    // 96x8192 bf16
    float*          U    = (float*)p;          p += 25165824;   // overlay: Uc[2][8192][320] / Ud[8][8192][96]
    float*          sinv1 = (float*)p;         p += 32768;
    float*          sinv2 = (float*)p;         p += 32768;

    if (both) {
        hipLaunchKernelGGL(k_prep_xw1, dim3(8832), dim3(256), 0, stream,
                           adj, mask1, mask2, P1, P2, sinv1, sinv2, x, w1, y, B1T);
    } else {
        hipLaunchKernelGGL(k_prep_xw1, dim3(8832), dim3(256), 0, stream,
                           adj, mask1, (const float*)nullptr, P1, (unsigned short*)nullptr,
                           sinv1, (float*)nullptr, x, w1, y, B1T);
    }
    hipLaunchKernelGGL(HIP_KERNEL_NAME(k_gemm<64, 2, 2, 2, 5>), dim3(640), dim3(256), 0, stream,
                       P1, B1T, U);
    hipLaunchKernelGGL(k_finC2,   dim3(256),  dim3(256), 0, stream, U, sinv1, b1, w2, B2T);
    if (!both) {
        hipLaunchKernelGGL(k_prep, dim3(8192), dim3(256), 0, stream,
                           adj, mask2, (const float*)nullptr, P1, (unsigned short*)nullptr,
                           sinv2, (float*)nullptr);
    }
    hipLaunchKernelGGL(HIP_KERNEL_NAME(k_gemm<96, 4, 1, 8, 1>), dim3(512), dim3(256), 0, stream,
                       P2, B2T, U);
    hipLaunchKernelGGL(k_finD,    dim3(256),  dim3(256), 0, stream, U, sinv2, b2, out);
}